// Round 1
// baseline (820.886 us; speedup 1.0000x reference)
//
#include <hip/hip_runtime.h>
#include <math.h>

constexpr int NB = 16;
constexpr int NC = 128;
constexpr int NS = 2048;          // Np1 == Mp1 == S
constexpr float F_INV_TEMP = 100.0f;
constexpr float F_EPS = 1e-5f;

#define NEG_INF (-__builtin_inff())

// ---- workspace layout (float offsets) ----
constexpr size_t RMAX_OFF = 1024;                                  // [NB*NS]
constexpr size_t RINV_OFF = RMAX_OFF + (size_t)NB * NS;            // [NB*NS]
constexpr size_t PMAX_OFF = RINV_OFF + (size_t)NB * NS;            // [NB*NS][32]
constexpr size_t PSUM_OFF = PMAX_OFF + (size_t)NB * NS * 32;       // [NB*NS][32]
constexpr size_t KP_OFF   = PSUM_OFF + (size_t)NB * NS * 32;       // k: [NB][NC][NS]
constexpr size_t VP_OFF   = KP_OFF + (size_t)NB * NC * NS;         // v: [NB][NC][NS]
// total = 10,552,320 floats = 42.2 MB

// ---------------- K0: ragged lengths ----------------
__global__ void k_lens(const int* __restrict__ lm_t, const int* __restrict__ lm_r,
                       int* __restrict__ lens) {
    int b = blockIdx.x & 15;
    const int* src = (blockIdx.x < 16) ? lm_t : lm_r;
    src += b * 4096;
    int m = 0;
    for (int i = threadIdx.x; i < 4096; i += 256) m = max(m, src[i]);
    for (int off = 32; off; off >>= 1) m = max(m, __shfl_down(m, off, 64));
    __shared__ int red[4];
    if ((threadIdx.x & 63) == 0) red[threadIdx.x >> 6] = m;
    __syncthreads();
    if (threadIdx.x == 0) {
        m = max(max(red[0], red[1]), max(red[2], red[3]));
        lens[blockIdx.x] = m + 1;   // [0..15]=len_t, [16..31]=len_r
    }
}

// ---------------- K1: fused center-norm + 1x1-conv projection ----------------
template <bool NORM>
__global__ __launch_bounds__(256) void k_proj(const float* __restrict__ x,
                                              const float* __restrict__ W,
                                              const float* __restrict__ bias,
                                              float* __restrict__ out) {
    __shared__ __align__(16) float xs[NC][64];
    __shared__ float ps[4][64], pq[4][64];
    __shared__ float cmean[64], cscale[64];
    const int b  = blockIdx.y;
    const int s0 = blockIdx.x * 64;
    const float* xb = x + (size_t)b * NC * NS + s0;

    for (int idx = threadIdx.x; idx < NC * 16; idx += 256) {
        int c = idx >> 4, j = (idx & 15) << 2;
        *(float4*)&xs[c][j] = *(const float4*)&xb[(size_t)c * NS + j];
    }
    __syncthreads();

    if (NORM) {
        int j = threadIdx.x & 63, p = threadIdx.x >> 6;
        float sum = 0.f, ssq = 0.f;
#pragma unroll
        for (int cc = 0; cc < 32; ++cc) {
            float v = xs[p * 32 + cc][j];
            sum += v; ssq += v * v;
        }
        ps[p][j] = sum; pq[p][j] = ssq;
        __syncthreads();
        if (threadIdx.x < 64) {
            float sm = ps[0][j] + ps[1][j] + ps[2][j] + ps[3][j];
            float sq = pq[0][j] + pq[1][j] + pq[2][j] + pq[3][j];
            float mean = sm * (1.f / NC);
            float var = sq - (float)NC * mean * mean;     // ||x-mean||^2
            cmean[j]  = mean;
            cscale[j] = 1.f / (sqrtf(fmaxf(var, 0.f)) + F_EPS);
        }
        __syncthreads();
        for (int idx = threadIdx.x; idx < NC * 64; idx += 256) {
            int c = idx >> 6, jj = idx & 63;
            xs[c][jj] = (xs[c][jj] - cmean[jj]) * cscale[jj];
        }
        __syncthreads();
    }

    // wave w computes channels [w*32, w*32+32), lane = column
    const int lane = threadIdx.x & 63;
    const int o0 = __builtin_amdgcn_readfirstlane((threadIdx.x >> 6) << 5);
    float acc[32];
#pragma unroll
    for (int i = 0; i < 32; ++i) acc[i] = 0.f;
    for (int c = 0; c < NC; ++c) {
        float xv = xs[c][lane];
#pragma unroll
        for (int oo = 0; oo < 32; ++oo)
            acc[oo] = fmaf(W[(size_t)(o0 + oo) * NC + c], xv, acc[oo]);
    }
    float* ob = out + (size_t)b * NC * NS + s0;
#pragma unroll
    for (int oo = 0; oo < 32; ++oo)
        ob[(size_t)(o0 + oo) * NS + lane] = acc[oo] + bias[o0 + oo];
}

// ---------------- K2: sim = 100*q^T k, masked, + online softmax partials ----------------
__global__ __launch_bounds__(256) void k_sim(const float* __restrict__ q,
                                             const float* __restrict__ k,
                                             const int* __restrict__ lens,
                                             float* __restrict__ att,
                                             float* __restrict__ pmax,
                                             float* __restrict__ psum) {
    __shared__ __align__(16) float qs[NC][64];
    __shared__ __align__(16) float ks[NC][64];
    const int b  = blockIdx.z;
    const int n0 = blockIdx.y * 64, m0 = blockIdx.x * 64;
    const float* qb = q + (size_t)b * NC * NS + n0;
    const float* kb = k + (size_t)b * NC * NS + m0;

    for (int idx = threadIdx.x; idx < NC * 16; idx += 256) {
        int c = idx >> 4, j = (idx & 15) << 2;
        *(float4*)&qs[c][j] = *(const float4*)&qb[(size_t)c * NS + j];
        *(float4*)&ks[c][j] = *(const float4*)&kb[(size_t)c * NS + j];
    }
    __syncthreads();

    const int tn = (threadIdx.x >> 4) << 2;   // row offset in tile (0..60)
    const int tm = (threadIdx.x & 15) << 2;   // col offset in tile (0..60)
    float acc[4][4] = {};
#pragma unroll 4
    for (int c = 0; c < NC; ++c) {
        float qv[4], kv[4];
        *(float4*)qv = *(const float4*)&qs[c][tn];
        *(float4*)kv = *(const float4*)&ks[c][tm];
#pragma unroll
        for (int i = 0; i < 4; ++i)
#pragma unroll
            for (int j = 0; j < 4; ++j)
                acc[i][j] = fmaf(qv[i], kv[j], acc[i][j]);
    }

    const int lenr = lens[16 + b];
#pragma unroll
    for (int i = 0; i < 4; ++i)
#pragma unroll
        for (int j = 0; j < 4; ++j)
            acc[i][j] = (m0 + tm + j < lenr) ? acc[i][j] * F_INV_TEMP : NEG_INF;

    float* ab = att + (size_t)b * NS * NS + (size_t)n0 * NS + m0;
#pragma unroll
    for (int i = 0; i < 4; ++i) {
        float4 w = make_float4(acc[i][0], acc[i][1], acc[i][2], acc[i][3]);
        *(float4*)&ab[(size_t)(tn + i) * NS + tm] = w;
    }

    // per-row partial max / sum-exp over this 64-col tile (16 lanes per row group)
#pragma unroll
    for (int i = 0; i < 4; ++i) {
        float m = fmaxf(fmaxf(acc[i][0], acc[i][1]), fmaxf(acc[i][2], acc[i][3]));
#pragma unroll
        for (int off = 1; off < 16; off <<= 1)
            m = fmaxf(m, __shfl_xor(m, off, 16));
        float s = 0.f;
        if (m > NEG_INF) {
#pragma unroll
            for (int j = 0; j < 4; ++j) s += __expf(acc[i][j] - m);
        }
#pragma unroll
        for (int off = 1; off < 16; off <<= 1)
            s += __shfl_xor(s, off, 16);
        if ((threadIdx.x & 15) == 0) {
            size_t row = (size_t)b * NS + n0 + tn + i;
            pmax[row * 32 + blockIdx.x] = m;
            psum[row * 32 + blockIdx.x] = s;
        }
    }
}

// ---------------- K3: combine partials -> rowmax, rowinv(+row mask) ----------------
__global__ void k_rowstats(const float* __restrict__ pmax, const float* __restrict__ psum,
                           const int* __restrict__ lens,
                           float* __restrict__ rmax, float* __restrict__ rinv) {
    int row = blockIdx.x * 256 + threadIdx.x;      // row = b*NS + n
    int b = row >> 11, n = row & (NS - 1);
    float M = NEG_INF;
    for (int t = 0; t < 32; ++t) M = fmaxf(M, pmax[(size_t)row * 32 + t]);
    float s = 0.f;
    for (int t = 0; t < 32; ++t) {
        float pm = pmax[(size_t)row * 32 + t];
        if (pm > NEG_INF) s += psum[(size_t)row * 32 + t] * __expf(pm - M);
    }
    rmax[row] = M;
    rinv[row] = (n < lens[b]) ? 1.f / s : 0.f;
}

// ---------------- K4: normalize att in place + PV GEMM + transposed store ----------------
constexpr int PADA = 68;    // atts[m][n] stride
constexpr int PADB = 132;   // vls[m][c] stride
__global__ __launch_bounds__(256) void k_pv(const float* __restrict__ v,
                                            const float* __restrict__ rmax,
                                            const float* __restrict__ rinv,
                                            float* __restrict__ att,
                                            float* __restrict__ out0) {
    __shared__ __align__(16) float As[64 * PADA];
    __shared__ __align__(16) float Bs[64 * PADB];
    __shared__ float rm_s[64], ri_s[64];
    const int b  = blockIdx.y;
    const int n0 = blockIdx.x * 64;

    if (threadIdx.x < 64) {
        rm_s[threadIdx.x] = rmax[(size_t)b * NS + n0 + threadIdx.x];
        ri_s[threadIdx.x] = rinv[(size_t)b * NS + n0 + threadIdx.x];
    }

    const int tng = threadIdx.x >> 5;   // 0..7  -> n = tng*8
    const int tcg = threadIdx.x & 31;   // 0..31 -> c = tcg*4
    float acc[8][4] = {};
    float* attb = att + (size_t)b * NS * NS + (size_t)n0 * NS;
    const float* vb = v + (size_t)b * NC * NS;

    for (int m0 = 0; m0 < NS; m0 += 64) {
        __syncthreads();   // rm_s ready (iter 0) / LDS free (iter >0)
        // stage att tile: normalize, write final att back, store transposed
        for (int idx = threadIdx.x; idx < 1024; idx += 256) {
            int n = idx >> 4, jm = (idx & 15) << 2;
            float4 r = *(const float4*)&attb[(size_t)n * NS + m0 + jm];
            float rm = rm_s[n], ri = ri_s[n];
            float4 o;
            o.x = __expf(r.x - rm) * ri;
            o.y = __expf(r.y - rm) * ri;
            o.z = __expf(r.z - rm) * ri;
            o.w = __expf(r.w - rm) * ri;
            *(float4*)&attb[(size_t)n * NS + m0 + jm] = o;
            As[(jm + 0) * PADA + n] = o.x;
            As[(jm + 1) * PADA + n] = o.y;
            As[(jm + 2) * PADA + n] = o.z;
            As[(jm + 3) * PADA + n] = o.w;
        }
        // stage v tile transposed: Bs[m][c]
        for (int idx = threadIdx.x; idx < 2048; idx += 256) {
            int c = idx >> 4, jm = (idx & 15) << 2;
            float4 r = *(const float4*)&vb[(size_t)c * NS + m0 + jm];
            Bs[(jm + 0) * PADB + c] = r.x;
            Bs[(jm + 1) * PADB + c] = r.y;
            Bs[(jm + 2) * PADB + c] = r.z;
            Bs[(jm + 3) * PADB + c] = r.w;
        }
        __syncthreads();
#pragma unroll 8
        for (int m = 0; m < 64; ++m) {
            float a0[8], b0[4];
            *(float4*)&a0[0] = *(const float4*)&As[m * PADA + tng * 8];
            *(float4*)&a0[4] = *(const float4*)&As[m * PADA + tng * 8 + 4];
            *(float4*)&b0[0] = *(const float4*)&Bs[m * PADB + tcg * 4];
#pragma unroll
            for (int i = 0; i < 8; ++i)
#pragma unroll
                for (int j = 0; j < 4; ++j)
                    acc[i][j] = fmaf(a0[i], b0[j], acc[i][j]);
        }
    }

    // transpose acc through LDS (reuse Bs) and store out0[b][c][n0+n] coalesced
    __syncthreads();
#pragma unroll
    for (int i = 0; i < 8; ++i) {
        float4 t = make_float4(acc[i][0], acc[i][1], acc[i][2], acc[i][3]);
        *(float4*)&Bs[(tng * 8 + i) * PADB + tcg * 4] = t;
    }
    __syncthreads();
    float* ob0 = out0 + (size_t)b * NC * NS + n0;
    for (int idx = threadIdx.x; idx < NC * 64; idx += 256) {
        int c = idx >> 6, n = idx & 63;
        ob0[(size_t)c * NS + n] = Bs[n * PADB + c];
    }
}

// ---------------- launch ----------------
extern "C" void kernel_launch(void* const* d_in, const int* in_sizes, int n_in,
                              void* d_out, int out_size, void* d_ws, size_t ws_size,
                              hipStream_t stream) {
    const float* xt   = (const float*)d_in[0];   // cat_encoded_target
    const float* xr   = (const float*)d_in[1];   // cat_encoded_ref
    const int*   lmt  = (const int*)d_in[2];
    const int*   lmr  = (const int*)d_in[3];
    const float* xrgb = (const float*)d_in[6];   // cat_encoded_rgb_ref
    const float* Wq   = (const float*)d_in[9];
    const float* bq   = (const float*)d_in[10];
    const float* Wk   = (const float*)d_in[11];
    const float* bk   = (const float*)d_in[12];
    const float* Wv   = (const float*)d_in[13];
    const float* bv   = (const float*)d_in[14];

    float* out0 = (float*)d_out;                       // [NB][NC][NS]
    float* att  = out0 + (size_t)NB * NC * NS;         // [NB][NS][NS]
    float* ws   = (float*)d_ws;
    int*   lens = (int*)d_ws;

    float* qbuf = out0;          // park q in the out0 region (out0 written only at the very end)
    float* kbuf = ws + KP_OFF;
    float* vbuf = ws + VP_OFF;

    k_lens<<<32, 256, 0, stream>>>(lmt, lmr, lens);

    dim3 gproj(NS / 64, NB);
    k_proj<true ><<<gproj, 256, 0, stream>>>(xt,   Wq, bq, qbuf);
    k_proj<true ><<<gproj, 256, 0, stream>>>(xr,   Wk, bk, kbuf);
    k_proj<false><<<gproj, 256, 0, stream>>>(xrgb, Wv, bv, vbuf);

    dim3 gsim(NS / 64, NS / 64, NB);
    k_sim<<<gsim, 256, 0, stream>>>(qbuf, kbuf, lens, att,
                                    ws + PMAX_OFF, ws + PSUM_OFF);

    k_rowstats<<<(NB * NS) / 256, 256, 0, stream>>>(ws + PMAX_OFF, ws + PSUM_OFF,
                                                    lens, ws + RMAX_OFF, ws + RINV_OFF);

    dim3 gpv(NS / 64, NB);
    k_pv<<<gpv, 256, 0, stream>>>(vbuf, ws + RMAX_OFF, ws + RINV_OFF, att, out0);
}

// Round 3
// 520.863 us; speedup vs baseline: 1.5760x; 1.5760x over previous
//
#include <hip/hip_runtime.h>
#include <math.h>

constexpr int NB = 16;
constexpr int NC = 128;
constexpr int NS = 2048;          // Np1 == Mp1 == S
constexpr float F_INV_TEMP = 100.0f;
constexpr float F_EPS = 1e-5f;
constexpr float NEGBIG = -1e30f;

typedef __attribute__((ext_vector_type(8))) _Float16 f16x8;
typedef __attribute__((ext_vector_type(4))) _Float16 f16x4;
typedef __attribute__((ext_vector_type(4))) float f32x4;

#define MFMA16(a, b, c) __builtin_amdgcn_mfma_f32_16x16x32_f16((a), (b), (c), 0, 0, 0)

// ---------------- K0: ragged lengths ----------------
__global__ void k_lens(const int* __restrict__ lm_t, const int* __restrict__ lm_r,
                       int* __restrict__ lens) {
    int b = blockIdx.x & 15;
    const int* src = (blockIdx.x < 16) ? lm_t : lm_r;
    src += b * 4096;
    int m = 0;
    for (int i = threadIdx.x; i < 4096; i += 256) m = max(m, src[i]);
    for (int off = 32; off; off >>= 1) m = max(m, __shfl_down(m, off, 64));
    __shared__ int red[4];
    if ((threadIdx.x & 63) == 0) red[threadIdx.x >> 6] = m;
    __syncthreads();
    if (threadIdx.x == 0) {
        m = max(max(red[0], red[1]), max(red[2], red[3]));
        lens[blockIdx.x] = m + 1;   // [0..15]=len_t, [16..31]=len_r
    }
}

// ---------------- K1: fused center-norm + 1x1-conv projection -> fp16 ----------------
// TRANSP=true : out[b][s][c]  (q, k — MFMA fragment friendly)
// TRANSP=false: out[b][c][s]  (v)
template <bool NORM, bool TRANSP>
__global__ __launch_bounds__(256) void k_proj(const float* __restrict__ x,
                                              const float* __restrict__ W,
                                              const float* __restrict__ bias,
                                              _Float16* __restrict__ out) {
    __shared__ __align__(16) float xs[NC][64];
    __shared__ float ps[4][64], pq[4][64];
    __shared__ float cmean[64], cscale[64];
    const int b  = blockIdx.y;
    const int s0 = blockIdx.x * 64;
    const float* xb = x + (size_t)b * NC * NS + s0;

    for (int idx = threadIdx.x; idx < NC * 16; idx += 256) {
        int c = idx >> 4, j = (idx & 15) << 2;
        *(float4*)&xs[c][j] = *(const float4*)&xb[(size_t)c * NS + j];
    }
    __syncthreads();

    if (NORM) {
        int j = threadIdx.x & 63, p = threadIdx.x >> 6;
        float sum = 0.f, ssq = 0.f;
#pragma unroll
        for (int cc = 0; cc < 32; ++cc) {
            float v = xs[p * 32 + cc][j];
            sum += v; ssq += v * v;
        }
        ps[p][j] = sum; pq[p][j] = ssq;
        __syncthreads();
        if (threadIdx.x < 64) {
            float sm = ps[0][j] + ps[1][j] + ps[2][j] + ps[3][j];
            float sq = pq[0][j] + pq[1][j] + pq[2][j] + pq[3][j];
            float mean = sm * (1.f / NC);
            float var = sq - (float)NC * mean * mean;     // ||x-mean||^2
            cmean[j]  = mean;
            cscale[j] = 1.f / (sqrtf(fmaxf(var, 0.f)) + F_EPS);
        }
        __syncthreads();
        for (int idx = threadIdx.x; idx < NC * 64; idx += 256) {
            int c = idx >> 6, jj = idx & 63;
            xs[c][jj] = (xs[c][jj] - cmean[jj]) * cscale[jj];
        }
        __syncthreads();
    }

    // wave w computes channels [w*32, w*32+32), lane = column s
    const int lane = threadIdx.x & 63;
    const int o0 = __builtin_amdgcn_readfirstlane((threadIdx.x >> 6) << 5);
    float acc[32];
#pragma unroll
    for (int i = 0; i < 32; ++i) acc[i] = 0.f;
    for (int c = 0; c < NC; ++c) {
        float xv = xs[c][lane];
#pragma unroll
        for (int oo = 0; oo < 32; ++oo)
            acc[oo] = fmaf(W[(size_t)(o0 + oo) * NC + c], xv, acc[oo]);
    }

    if (TRANSP) {
        _Float16 us[32];
#pragma unroll
        for (int oo = 0; oo < 32; ++oo) us[oo] = (_Float16)(acc[oo] + bias[o0 + oo]);
        _Float16* orow = out + ((size_t)b * NS + s0 + lane) * NC + o0;
#pragma unroll
        for (int i = 0; i < 4; ++i) *(f16x8*)(orow + i * 8) = *(f16x8*)&us[i * 8];
    } else {
#pragma unroll
        for (int oo = 0; oo < 32; ++oo)
            out[((size_t)b * NC + o0 + oo) * NS + s0 + lane] =
                (_Float16)(acc[oo] + bias[o0 + oo]);
    }
}

// ---------------- K2: fused attention (2-pass recompute, MFMA) ----------------
// Layouts: qt,kt = [b][s][c] fp16 ; vt = [b][c][s] fp16
// Swapped QK^T: D = K_tile(16m x 32c) * Q_frag(32c x 16n): lane holds col n=l&15,
// rows m=(l>>4)*4+r  -> row-softmax stats are per-lane over m, reduce over l>>4 groups.
__global__ __launch_bounds__(256) void k_attn(const _Float16* __restrict__ qt,
                                              const _Float16* __restrict__ kt,
                                              const _Float16* __restrict__ vt,
                                              const int* __restrict__ lens,
                                              float* __restrict__ att,
                                              float* __restrict__ out0) {
    __shared__ _Float16 Plds[4][16][40];  // per-wave P tile [n][m], stride 40 (80B: 16B-aligned b128 reads)
    const int b  = blockIdx.x >> 5;       // consecutive blocks share b -> L2 locality
    const int nt = blockIdx.x & 31;
    const int w    = threadIdx.x >> 6;
    const int lane = threadIdx.x & 63;
    const int ln = lane & 15;
    const int g  = lane >> 4;
    const int n_base = nt * 64 + w * 16;
    const int lenq = lens[b], lenr = lens[16 + b];

    // Q B-fragments for this wave's 16 n (fixed for the whole kernel)
    const _Float16* qrow = qt + ((size_t)b * NS + n_base + ln) * NC + g * 8;
    const f16x8 qf0 = *(const f16x8*)(qrow +  0);
    const f16x8 qf1 = *(const f16x8*)(qrow + 32);
    const f16x8 qf2 = *(const f16x8*)(qrow + 64);
    const f16x8 qf3 = *(const f16x8*)(qrow + 96);

    const _Float16* kb = kt + (size_t)b * NS * NC;   // [m][c]
    const _Float16* vb = vt + (size_t)b * NC * NS;   // [c][m]

    // ---------- pass 1: row max / sum (online) ----------
    float mrun = NEGBIG, srun = 0.f;
    for (int m0 = 0; m0 < lenr; m0 += 32) {
        const _Float16* kr0 = kb + (size_t)(m0 + ln) * NC + g * 8;
        const _Float16* kr1 = kr0 + 16 * NC;
        f32x4 a0 = {0.f, 0.f, 0.f, 0.f}, a1 = {0.f, 0.f, 0.f, 0.f};
        a0 = MFMA16(*(const f16x8*)(kr0 +  0), qf0, a0);
        a0 = MFMA16(*(const f16x8*)(kr0 + 32), qf1, a0);
        a0 = MFMA16(*(const f16x8*)(kr0 + 64), qf2, a0);
        a0 = MFMA16(*(const f16x8*)(kr0 + 96), qf3, a0);
        a1 = MFMA16(*(const f16x8*)(kr1 +  0), qf0, a1);
        a1 = MFMA16(*(const f16x8*)(kr1 + 32), qf1, a1);
        a1 = MFMA16(*(const f16x8*)(kr1 + 64), qf2, a1);
        a1 = MFMA16(*(const f16x8*)(kr1 + 96), qf3, a1);

        float vv[8];
#pragma unroll
        for (int r = 0; r < 4; ++r) {
            int mi = m0 + 4 * g + r;
            vv[r]     = (mi      < lenr) ? a0[r] * F_INV_TEMP : NEGBIG;
            vv[4 + r] = (mi + 16 < lenr) ? a1[r] * F_INV_TEMP : NEGBIG;
        }
        float cmax = fmaxf(fmaxf(fmaxf(vv[0], vv[1]), fmaxf(vv[2], vv[3])),
                           fmaxf(fmaxf(vv[4], vv[5]), fmaxf(vv[6], vv[7])));
        float newm = fmaxf(mrun, cmax);
        float ssum = 0.f;
#pragma unroll
        for (int i = 0; i < 8; ++i) ssum += __expf(vv[i] - newm);
        srun = srun * __expf(mrun - newm) + ssum;
        mrun = newm;
    }
    // reduce across the 4 row-groups (lanes l^16, l^32 share the same n)
#pragma unroll
    for (int off = 16; off <= 32; off <<= 1) {
        float om = __shfl_xor(mrun, off, 64);
        float os = __shfl_xor(srun, off, 64);
        float nm = fmaxf(mrun, om);
        srun = srun * __expf(mrun - nm) + os * __expf(om - nm);
        mrun = nm;
    }
    const float M = mrun;
    const float rinv = ((n_base + ln) < lenq) ? (1.0f / srun) : 0.0f;

    // ---------- pass 2: recompute, write att, accumulate PV ----------
    f32x4 opv[8];
#pragma unroll
    for (int ct = 0; ct < 8; ++ct) opv[ct] = f32x4{0.f, 0.f, 0.f, 0.f};

    float* attb = att + ((size_t)b * NS + n_base + ln) * NS;   // this lane's n-row

    for (int m0 = 0; m0 < NS; m0 += 32) {
        if (m0 >= lenr) {
            f32x4 z = {0.f, 0.f, 0.f, 0.f};
            *(f32x4*)(attb + m0 + 4 * g)      = z;
            *(f32x4*)(attb + m0 + 16 + 4 * g) = z;
            continue;
        }
        const _Float16* kr0 = kb + (size_t)(m0 + ln) * NC + g * 8;
        const _Float16* kr1 = kr0 + 16 * NC;
        f32x4 a0 = {0.f, 0.f, 0.f, 0.f}, a1 = {0.f, 0.f, 0.f, 0.f};
        a0 = MFMA16(*(const f16x8*)(kr0 +  0), qf0, a0);
        a0 = MFMA16(*(const f16x8*)(kr0 + 32), qf1, a0);
        a0 = MFMA16(*(const f16x8*)(kr0 + 64), qf2, a0);
        a0 = MFMA16(*(const f16x8*)(kr0 + 96), qf3, a0);
        a1 = MFMA16(*(const f16x8*)(kr1 +  0), qf0, a1);
        a1 = MFMA16(*(const f16x8*)(kr1 + 32), qf1, a1);
        a1 = MFMA16(*(const f16x8*)(kr1 + 64), qf2, a1);
        a1 = MFMA16(*(const f16x8*)(kr1 + 96), qf3, a1);

        f32x4 p0, p1;
#pragma unroll
        for (int r = 0; r < 4; ++r) {
            int mi = m0 + 4 * g + r;
            float v0 = (mi      < lenr) ? a0[r] * F_INV_TEMP : NEGBIG;
            float v1 = (mi + 16 < lenr) ? a1[r] * F_INV_TEMP : NEGBIG;
            p0[r] = __expf(v0 - M) * rinv;   // masked -> exp(-1e30-M) == 0
            p1[r] = __expf(v1 - M) * rinv;
        }
        // final att (fp32, written exactly once, float4)
        *(f32x4*)(attb + m0 + 4 * g)      = p0;
        *(f32x4*)(attb + m0 + 16 + 4 * g) = p1;

        // P -> fp16 -> LDS [n][m] for PV A-fragments (per-wave private tile)
        f16x4 pk0, pk1;
#pragma unroll
        for (int r = 0; r < 4; ++r) {
            pk0[r] = (_Float16)p0[r];
            pk1[r] = (_Float16)p1[r];
        }
        *(f16x4*)&Plds[w][ln][4 * g]      = pk0;
        *(f16x4*)&Plds[w][ln][16 + 4 * g] = pk1;
        // same-wave LDS write->read: in-order DS pipe; compiler inserts lgkmcnt
        f16x8 pf = *(const f16x8*)&Plds[w][ln][g * 8];   // A-frag: row n=l&15, k m=(l>>4)*8+j

        const _Float16* vr = vb + (size_t)ln * NS + m0 + g * 8;
#pragma unroll
        for (int ct = 0; ct < 8; ++ct) {
            f16x8 vf = *(const f16x8*)(vr + (size_t)ct * 16 * NS);  // B-frag: col c, k m
            opv[ct] = MFMA16(pf, vf, opv[ct]);
        }
    }

    // store out0[b][c][n]: lane holds col c=ct*16+ln, rows n=n_base+4g+r (contiguous)
    float* ob = out0 + (size_t)b * NC * NS;
#pragma unroll
    for (int ct = 0; ct < 8; ++ct)
        *(f32x4*)(ob + (size_t)(ct * 16 + ln) * NS + n_base + 4 * g) = opv[ct];
}

// ---------------- launch ----------------
extern "C" void kernel_launch(void* const* d_in, const int* in_sizes, int n_in,
                              void* d_out, int out_size, void* d_ws, size_t ws_size,
                              hipStream_t stream) {
    const float* xt   = (const float*)d_in[0];   // cat_encoded_target
    const float* xr   = (const float*)d_in[1];   // cat_encoded_ref
    const int*   lmt  = (const int*)d_in[2];
    const int*   lmr  = (const int*)d_in[3];
    const float* xrgb = (const float*)d_in[6];   // cat_encoded_rgb_ref
    const float* Wq   = (const float*)d_in[9];
    const float* bq   = (const float*)d_in[10];
    const float* Wk   = (const float*)d_in[11];
    const float* bk   = (const float*)d_in[12];
    const float* Wv   = (const float*)d_in[13];
    const float* bv   = (const float*)d_in[14];

    float* out0 = (float*)d_out;                       // [NB][NC][NS]
    float* att  = out0 + (size_t)NB * NC * NS;         // [NB][NS][NS]

    int*      lens = (int*)d_ws;
    _Float16* qt = (_Float16*)((char*)d_ws + 1024);    // [NB][NS][NC] fp16
    _Float16* kt = qt + (size_t)NB * NS * NC;          // [NB][NS][NC] fp16
    _Float16* vt = kt + (size_t)NB * NS * NC;          // [NB][NC][NS] fp16

    k_lens<<<32, 256, 0, stream>>>(lmt, lmr, lens);

    dim3 gproj(NS / 64, NB);
    k_proj<true,  true ><<<gproj, 256, 0, stream>>>(xt,   Wq, bq, qt);
    k_proj<true,  true ><<<gproj, 256, 0, stream>>>(xr,   Wk, bk, kt);
    k_proj<false, false><<<gproj, 256, 0, stream>>>(xrgb, Wv, bv, vt);

    k_attn<<<NB * 32, 256, 0, stream>>>(qt, kt, vt, lens, att, out0);
}

// Round 4
// 271.460 us; speedup vs baseline: 3.0240x; 1.9187x over previous
//
#include <hip/hip_runtime.h>
#include <math.h>

constexpr int NB = 16;
constexpr int NC = 128;
constexpr int NS = 2048;          // Np1 == Mp1 == S
constexpr float F_INV_TEMP = 100.0f;
constexpr float F_EPS = 1e-5f;
constexpr float NEGBIG = -1e30f;
constexpr int CHA = 4;            // stats m-chunks (512 each)
constexpr int CHB = 2;            // pass-B m-chunks (1024 each)

typedef __attribute__((ext_vector_type(8))) _Float16 f16x8;
typedef __attribute__((ext_vector_type(4))) _Float16 f16x4;
typedef __attribute__((ext_vector_type(4))) float f32x4;

#define MFMA16(a, b, c) __builtin_amdgcn_mfma_f32_16x16x32_f16((a), (b), (c), 0, 0, 0)

// ---- workspace layout (float offsets) ----
constexpr size_t RM_OFF = 64;                        // rowmax [NB*NS]
constexpr size_t RI_OFF = RM_OFF + (size_t)NB * NS;  // rowinv [NB*NS]
constexpr size_t PM_OFF = RI_OFF + (size_t)NB * NS;  // partial max [NB*NS][CHA]
constexpr size_t PS_OFF = PM_OFF + (size_t)NB * NS * CHA;
constexpr size_t F16_OFF = PS_OFF + (size_t)NB * NS * CHA;
// fp16 region (element offsets):
constexpr size_t QT_H   = 0;                                  // q (in-place over xn_t) [b][s][c]
constexpr size_t KT_H   = QT_H + (size_t)NB * NS * NC;        // k (in-place over xn_r) [b][s][c]
constexpr size_t XRGB_H = KT_H + (size_t)NB * NS * NC;        // xn_rgb [b][s][c]
constexpr size_t VT_H   = XRGB_H + (size_t)NB * NS * NC;      // v [b][c][s]
constexpr size_t W16_H  = VT_H + (size_t)NB * NS * NC;        // W16 [3][128][128]

// ---------------- K0: ragged lengths ----------------
__global__ void k_lens(const int* __restrict__ lm_t, const int* __restrict__ lm_r,
                       int* __restrict__ lens) {
    int b = blockIdx.x & 15;
    const int* src = (blockIdx.x < 16) ? lm_t : lm_r;
    src += b * 4096;
    int m = 0;
    for (int i = threadIdx.x; i < 4096; i += 256) m = max(m, src[i]);
    for (int off = 32; off; off >>= 1) m = max(m, __shfl_down(m, off, 64));
    __shared__ int red[4];
    if ((threadIdx.x & 63) == 0) red[threadIdx.x >> 6] = m;
    __syncthreads();
    if (threadIdx.x == 0) {
        m = max(max(red[0], red[1]), max(red[2], red[3]));
        lens[blockIdx.x] = m + 1;   // [0..15]=len_t, [16..31]=len_r
    }
}

// ---------------- K0b: convert W to fp16 ----------------
__global__ void k_prep(const float* __restrict__ Wq, const float* __restrict__ Wk,
                       const float* __restrict__ Wv, _Float16* __restrict__ W16) {
    int i = blockIdx.x * 256 + threadIdx.x;          // grid 64 -> 16384
    W16[i]               = (_Float16)Wq[i];
    W16[i + NC * NC]     = (_Float16)Wk[i];
    W16[i + 2 * NC * NC] = (_Float16)Wv[i];
}

// ---------------- K1: center-norm + transpose -> fp16 [b][s][c] ----------------
template <bool NORM>
__global__ __launch_bounds__(256) void k_norm(const float* __restrict__ x,
                                              _Float16* __restrict__ out) {
    __shared__ __align__(16) float xs[NC][64];
    __shared__ float ps[4][64], pq[4][64];
    __shared__ float cmean[64], cscale[64];
    const int b  = blockIdx.y;
    const int s0 = blockIdx.x * 64;
    const float* xb = x + (size_t)b * NC * NS + s0;

    for (int idx = threadIdx.x; idx < NC * 16; idx += 256) {
        int c = idx >> 4, j = (idx & 15) << 2;
        *(float4*)&xs[c][j] = *(const float4*)&xb[(size_t)c * NS + j];
    }
    __syncthreads();

    if (NORM) {
        int j = threadIdx.x & 63, p = threadIdx.x >> 6;
        float sum = 0.f, ssq = 0.f;
#pragma unroll
        for (int cc = 0; cc < 32; ++cc) {
            float v = xs[p * 32 + cc][j];
            sum += v; ssq += v * v;
        }
        ps[p][j] = sum; pq[p][j] = ssq;
        __syncthreads();
        if (threadIdx.x < 64) {
            float sm = ps[0][j] + ps[1][j] + ps[2][j] + ps[3][j];
            float sq = pq[0][j] + pq[1][j] + pq[2][j] + pq[3][j];
            float mean = sm * (1.f / NC);
            float var = sq - (float)NC * mean * mean;
            cmean[j]  = mean;
            cscale[j] = 1.f / (sqrtf(fmaxf(var, 0.f)) + F_EPS);
        }
        __syncthreads();
    }

    const int lane = threadIdx.x & 63;        // s column
    const int o0 = (threadIdx.x >> 6) * 32;   // c chunk
    _Float16 us[32];
    if (NORM) {
        float mn = cmean[lane], sc = cscale[lane];
#pragma unroll
        for (int i = 0; i < 32; ++i) us[i] = (_Float16)((xs[o0 + i][lane] - mn) * sc);
    } else {
#pragma unroll
        for (int i = 0; i < 32; ++i) us[i] = (_Float16)xs[o0 + i][lane];
    }
    _Float16* orow = out + ((size_t)b * NS + s0 + lane) * NC + o0;
#pragma unroll
    for (int i = 0; i < 4; ++i) *(f16x8*)(orow + i * 8) = *(f16x8*)&us[i * 8];
}

// ---------------- K2: projection GEMM via MFMA ----------------
// MODE 0/1: out = xn (in-place, [b][s][c]); MODE 2: out -> vout [b][c][s] via LDS transpose
template <int MODE>
__global__ __launch_bounds__(256) void k_projmm(_Float16* __restrict__ xn,
                                                const _Float16* __restrict__ W16,
                                                const float* __restrict__ bias,
                                                _Float16* __restrict__ vout) {
    __shared__ _Float16 Vt[NC][72];   // MODE==2 only (72: bank spread + 16B-aligned rows)
    const int b  = blockIdx.y;
    const int s0 = blockIdx.x * 64;
    const int w = threadIdx.x >> 6, lane = threadIdx.x & 63;
    const int ln = lane & 15, g = lane >> 4;
    const int srow = s0 + w * 16 + ln;

    const _Float16* arow = xn + ((size_t)b * NS + srow) * NC + g * 8;
    const f16x8 xf0 = *(const f16x8*)(arow);
    const f16x8 xf1 = *(const f16x8*)(arow + 32);
    const f16x8 xf2 = *(const f16x8*)(arow + 64);
    const f16x8 xf3 = *(const f16x8*)(arow + 96);

#pragma unroll
    for (int ot = 0; ot < 8; ++ot) {
        const _Float16* wrow = W16 + (size_t)(ot * 16 + ln) * NC + g * 8;
        f32x4 acc = {0.f, 0.f, 0.f, 0.f};
        acc = MFMA16(*(const f16x8*)(wrow),      xf0, acc);
        acc = MFMA16(*(const f16x8*)(wrow + 32), xf1, acc);
        acc = MFMA16(*(const f16x8*)(wrow + 64), xf2, acc);
        acc = MFMA16(*(const f16x8*)(wrow + 96), xf3, acc);
        // lane holds out[o = ot*16 + 4g + r][s = srow]
        const float4 bv = *(const float4*)&bias[ot * 16 + 4 * g];
        f16x4 res;
        res[0] = (_Float16)(acc[0] + bv.x);
        res[1] = (_Float16)(acc[1] + bv.y);
        res[2] = (_Float16)(acc[2] + bv.z);
        res[3] = (_Float16)(acc[3] + bv.w);
        if (MODE < 2) {
            *(f16x4*)(xn + ((size_t)b * NS + srow) * NC + ot * 16 + 4 * g) = res;
        } else {
#pragma unroll
            for (int r = 0; r < 4; ++r)
                Vt[ot * 16 + 4 * g + r][w * 16 + ln] = res[r];
        }
    }
    if (MODE == 2) {
        __syncthreads();
        int o = threadIdx.x >> 1, sh = threadIdx.x & 1;
        _Float16* vr = vout + ((size_t)b * NC + o) * NS + s0 + sh * 32;
        const _Float16* src = &Vt[o][sh * 32];
#pragma unroll
        for (int i = 0; i < 4; ++i) *(f16x8*)(vr + i * 8) = *(const f16x8*)(src + i * 8);
    }
}

// ---- stage K tile [64][128] fp16 into LDS with XOR slot swizzle ----
__device__ __forceinline__ void stage_k_tile(_Float16* Klds, const _Float16* kb,
                                             int mg0, int tid) {
#pragma unroll
    for (int q = 0; q < 4; ++q) {
        int t16 = q * 256 + tid;
        int r = t16 >> 4, s = t16 & 15;
        f16x8 val = *(const f16x8*)(kb + (size_t)(mg0 + r) * NC + s * 8);
        *(f16x8*)(Klds + r * 128 + ((s ^ (r & 7)) << 3)) = val;
    }
}

// ---------------- K3: partial softmax stats (split-m) ----------------
__global__ __launch_bounds__(256, 4) void k_stats(const _Float16* __restrict__ qt,
                                                  const _Float16* __restrict__ kt,
                                                  const int* __restrict__ lens,
                                                  float* __restrict__ pM,
                                                  float* __restrict__ pS) {
    __shared__ _Float16 Klds[64 * 128];
    const int nt = blockIdx.x, ch = blockIdx.y, b = blockIdx.z;
    const int tid = threadIdx.x;
    const int w = tid >> 6, lane = tid & 63, ln = lane & 15, g = lane >> 4;
    const int n_base = nt * 64 + w * 16;
    const int lenr = lens[16 + b];
    const int swz = ln & 7;

    const _Float16* qrow = qt + ((size_t)b * NS + n_base + ln) * NC + g * 8;
    f16x8 qf[4];
#pragma unroll
    for (int j = 0; j < 4; ++j) qf[j] = *(const f16x8*)(qrow + 32 * j);

    const _Float16* kb = kt + (size_t)b * NS * NC;

    float mrun = NEGBIG, srun = 0.f;
    const int m_end = min((ch + 1) * (NS / CHA), lenr);
    for (int mg0 = ch * (NS / CHA); mg0 < m_end; mg0 += 64) {
        __syncthreads();
        stage_k_tile(Klds, kb, mg0, tid);
        __syncthreads();
#pragma unroll
        for (int half = 0; half < 2; ++half) {
            const int m0 = half * 32;
            f32x4 a0 = {0.f, 0.f, 0.f, 0.f}, a1 = {0.f, 0.f, 0.f, 0.f};
#pragma unroll
            for (int j = 0; j < 4; ++j) {
                f16x8 k0 = *(const f16x8*)(Klds + (m0 + ln) * 128 + ((((j << 2) + g) ^ swz) << 3));
                f16x8 k1 = *(const f16x8*)(Klds + (m0 + 16 + ln) * 128 + ((((j << 2) + g) ^ swz) << 3));
                a0 = MFMA16(k0, qf[j], a0);
                a1 = MFMA16(k1, qf[j], a1);
            }
            float vv[8];
#pragma unroll
            for (int r = 0; r < 4; ++r) {
                int mi = mg0 + m0 + 4 * g + r;
                vv[r]     = (mi      < lenr) ? a0[r] * F_INV_TEMP : NEGBIG;
                vv[4 + r] = (mi + 16 < lenr) ? a1[r] * F_INV_TEMP : NEGBIG;
            }
            float cmax = fmaxf(fmaxf(fmaxf(vv[0], vv[1]), fmaxf(vv[2], vv[3])),
                               fmaxf(fmaxf(vv[4], vv[5]), fmaxf(vv[6], vv[7])));
            float newm = fmaxf(mrun, cmax);
            float ssum = 0.f;
#pragma unroll
            for (int i = 0; i < 8; ++i) ssum += __expf(vv[i] - newm);
            srun = srun * __expf(mrun - newm) + ssum;
            mrun = newm;
        }
    }
#pragma unroll
    for (int off = 16; off <= 32; off <<= 1) {
        float om = __shfl_xor(mrun, off, 64);
        float os = __shfl_xor(srun, off, 64);
        float nm = fmaxf(mrun, om);
        srun = srun * __expf(mrun - nm) + os * __expf(om - nm);
        mrun = nm;
    }
    if (g == 0) {
        size_t row = (size_t)b * NS + n_base + ln;
        pM[row * CHA + ch] = mrun;
        pS[row * CHA + ch] = srun;
    }
}

// ---------------- K4: combine partials ----------------
__global__ void k_combine(const float* __restrict__ pM, const float* __restrict__ pS,
                          const int* __restrict__ lens,
                          float* __restrict__ rM, float* __restrict__ rI) {
    int row = blockIdx.x * 256 + threadIdx.x;       // 32768 rows
    int b = row >> 11, n = row & (NS - 1);
    float M = NEGBIG;
#pragma unroll
    for (int c = 0; c < CHA; ++c) M = fmaxf(M, pM[(size_t)row * CHA + c]);
    float S = 0.f;
#pragma unroll
    for (int c = 0; c < CHA; ++c) {
        float pm = pM[(size_t)row * CHA + c];
        if (pm > -1e29f) S += pS[(size_t)row * CHA + c] * __expf(pm - M);
    }
    rM[row] = M;
    rI[row] = (n < lens[b]) ? 1.f / S : 0.f;
}

// ---------------- K5: pass B — recompute QK^T, write att, partial PV ----------------
__global__ __launch_bounds__(256, 4) void k_attn2(const _Float16* __restrict__ qt,
                                                  const _Float16* __restrict__ kt,
                                                  const _Float16* __restrict__ vt,
                                                  const int* __restrict__ lens,
                                                  const float* __restrict__ rM,
                                                  const float* __restrict__ rI,
                                                  float* __restrict__ att,
                                                  float* __restrict__ out0) {
    __shared__ _Float16 Klds[64 * 128];
    __shared__ _Float16 Vlds[128 * 64];
    __shared__ _Float16 Plds[4][16][40];
    const int nt = blockIdx.x, ch = blockIdx.y, b = blockIdx.z;
    const int tid = threadIdx.x;
    const int w = tid >> 6, lane = tid & 63, ln = lane & 15, g = lane >> 4;
    const int n_base = nt * 64 + w * 16;
    const int lenr = lens[16 + b];
    const int swz = ln & 7;

    const _Float16* qrow = qt + ((size_t)b * NS + n_base + ln) * NC + g * 8;
    f16x8 qf[4];
#pragma unroll
    for (int j = 0; j < 4; ++j) qf[j] = *(const f16x8*)(qrow + 32 * j);

    const _Float16* kb = kt + (size_t)b * NS * NC;   // [m][c]
    const _Float16* vb = vt + (size_t)b * NC * NS;   // [c][m]

    const size_t row = (size_t)b * NS + n_base + ln;
    const float M = rM[row];
    const float rinv = rI[row];

    f32x4 opv[8];
#pragma unroll
    for (int ct = 0; ct < 8; ++ct) opv[ct] = f32x4{0.f, 0.f, 0.f, 0.f};

    float* attb = att + row * NS;

    for (int it = 0; it < (NS / CHB) / 64; ++it) {
        const int mg0 = ch * (NS / CHB) + it * 64;
        const bool live = (mg0 < lenr);              // block-uniform
        __syncthreads();
        if (live) {
            stage_k_tile(Klds, kb, mg0, tid);
#pragma unroll
            for (int q = 0; q < 4; ++q) {
                int t16 = q * 256 + tid;
                int rv = t16 >> 3, sv = t16 & 7;
                f16x8 val = *(const f16x8*)(vb + (size_t)rv * NS + mg0 + sv * 8);
                *(f16x8*)(Vlds + rv * 64 + ((sv ^ (rv & 7)) << 3)) = val;
            }
        }
        __syncthreads();
        if (!live) {
            f32x4 z = {0.f, 0.f, 0.f, 0.f};
#pragma unroll
            for (int h = 0; h < 4; ++h)
                *(f32x4*)(attb + mg0 + h * 16 + 4 * g) = z;
            continue;
        }
#pragma unroll
        for (int half = 0; half < 2; ++half) {
            const int m0 = half * 32;
            f32x4 a0 = {0.f, 0.f, 0.f, 0.f}, a1 = {0.f, 0.f, 0.f, 0.f};
#pragma unroll
            for (int j = 0; j < 4; ++j) {
                f16x8 k0 = *(const f16x8*)(Klds + (m0 + ln) * 128 + ((((j << 2) + g) ^ swz) << 3));
                f16x8 k1 = *(const f16x8*)(Klds + (m0 + 16 + ln) * 128 + ((((j << 2) + g) ^ swz) << 3));
                a0 = MFMA16(k0, qf[j], a0);
                a1 = MFMA16(k1, qf[j], a1);
            }
            f32x4 p0, p1;
#pragma unroll
            for (int r = 0; r < 4; ++r) {
                int mi = mg0 + m0 + 4 * g + r;
                float v0 = (mi      < lenr) ? a0[r] * F_INV_TEMP : NEGBIG;
                float v1 = (mi + 16 < lenr) ? a1[r] * F_INV_TEMP : NEGBIG;
                p0[r] = __expf(v0 - M) * rinv;
                p1[r] = __expf(v1 - M) * rinv;
            }
            *(f32x4*)(attb + mg0 + m0 + 4 * g)      = p0;
            *(f32x4*)(attb + mg0 + m0 + 16 + 4 * g) = p1;

            f16x4 pk0, pk1;
#pragma unroll
            for (int r = 0; r < 4; ++r) {
                pk0[r] = (_Float16)p0[r];
                pk1[r] = (_Float16)p1[r];
            }
            *(f16x4*)&Plds[w][ln][4 * g]      = pk0;
            *(f16x4*)&Plds[w][ln][16 + 4 * g] = pk1;
            f16x8 pf = *(const f16x8*)&Plds[w][ln][g * 8];

#pragma unroll
            for (int ct = 0; ct < 8; ++ct) {
                f16x8 vf = *(const f16x8*)(Vlds + (ct * 16 + ln) * 64 +
                                           (((half * 4 + g) ^ swz) << 3));
                opv[ct] = MFMA16(pf, vf, opv[ct]);
            }
        }
    }

    // partial PV -> out0 (exactly CHB=2 adds per element: bitwise deterministic)
    float* ob = out0 + (size_t)b * NC * NS;
#pragma unroll
    for (int ct = 0; ct < 8; ++ct) {
        float* dst = ob + (size_t)(ct * 16 + ln) * NS + n_base + 4 * g;
#pragma unroll
        for (int r = 0; r < 4; ++r) unsafeAtomicAdd(dst + r, opv[ct][r]);
    }
}

// ---------------- launch ----------------
extern "C" void kernel_launch(void* const* d_in, const int* in_sizes, int n_in,
                              void* d_out, int out_size, void* d_ws, size_t ws_size,
                              hipStream_t stream) {
    const float* xt   = (const float*)d_in[0];
    const float* xr   = (const float*)d_in[1];
    const int*   lmt  = (const int*)d_in[2];
    const int*   lmr  = (const int*)d_in[3];
    const float* xrgb = (const float*)d_in[6];
    const float* Wq   = (const float*)d_in[9];
    const float* bq   = (const float*)d_in[10];
    const float* Wk   = (const float*)d_in[11];
    const float* bk   = (const float*)d_in[12];
    const float* Wv   = (const float*)d_in[13];
    const float* bv   = (const float*)d_in[14];

    float* out0 = (float*)d_out;                       // [NB][NC][NS]
    float* att  = out0 + (size_t)NB * NC * NS;         // [NB][NS][NS]

    float* ws   = (float*)d_ws;
    int*   lens = (int*)d_ws;
    _Float16* h = (_Float16*)(ws + F16_OFF);
    _Float16* qt    = h + QT_H;
    _Float16* kt    = h + KT_H;
    _Float16* xnrgb = h + XRGB_H;
    _Float16* vt    = h + VT_H;
    _Float16* W16   = h + W16_H;

    k_lens<<<32, 256, 0, stream>>>(lmt, lmr, lens);
    k_prep<<<NC * NC / 256, 256, 0, stream>>>(Wq, Wk, Wv, W16);

    dim3 gnorm(NS / 64, NB);
    k_norm<true ><<<gnorm, 256, 0, stream>>>(xt,   qt);      // xn_t (becomes q in-place)
    k_norm<true ><<<gnorm, 256, 0, stream>>>(xr,   kt);      // xn_r (becomes k in-place)
    k_norm<false><<<gnorm, 256, 0, stream>>>(xrgb, xnrgb);

    k_projmm<0><<<gnorm, 256, 0, stream>>>(qt,    W16,               bq, (_Float16*)nullptr);
    k_projmm<1><<<gnorm, 256, 0, stream>>>(kt,    W16 + NC * NC,     bk, (_Float16*)nullptr);
    k_projmm<2><<<gnorm, 256, 0, stream>>>(xnrgb, W16 + 2 * NC * NC, bv, vt);

    dim3 gstats(NS / 64, CHA, NB);
    k_stats<<<gstats, 256, 0, stream>>>(qt, kt, lens, ws + PM_OFF, ws + PS_OFF);
    k_combine<<<(NB * NS) / 256, 256, 0, stream>>>(ws + PM_OFF, ws + PS_OFF, lens,
                                                   ws + RM_OFF, ws + RI_OFF);

    hipMemsetAsync(out0, 0, (size_t)NB * NC * NS * sizeof(float), stream);

    dim3 gattn(NS / 64, CHB, NB);
    k_attn2<<<gattn, 256, 0, stream>>>(qt, kt, vt, lens, ws + RM_OFF, ws + RI_OFF,
                                       att, out0);
}

// Round 5
// 252.057 us; speedup vs baseline: 3.2567x; 1.0770x over previous
//
#include <hip/hip_runtime.h>
#include <math.h>

constexpr int NB = 16;
constexpr int NC = 128;
constexpr int NS = 2048;          // Np1 == Mp1 == S
constexpr float F_INV_TEMP = 100.0f;
constexpr float F_EPS = 1e-5f;
constexpr float NEGBIG = -1e30f;
constexpr int CHA = 4;            // stats m-chunks (512 each)
constexpr int CHB = 2;            // pass-B m-chunks (1024 each)

typedef __attribute__((ext_vector_type(8))) _Float16 f16x8;
typedef __attribute__((ext_vector_type(4))) _Float16 f16x4;
typedef __attribute__((ext_vector_type(4))) float f32x4;

#define MFMA16(a, b, c) __builtin_amdgcn_mfma_f32_16x16x32_f16((a), (b), (c), 0, 0, 0)

// ---- workspace layout (float offsets) ----
constexpr size_t RM_OFF = 64;                        // rowmax [NB*NS]
constexpr size_t RI_OFF = RM_OFF + (size_t)NB * NS;  // rowinv [NB*NS]
constexpr size_t PM_OFF = RI_OFF + (size_t)NB * NS;  // partial max [NB*NS][CHA]
constexpr size_t PS_OFF = PM_OFF + (size_t)NB * NS * CHA;
constexpr size_t F16_OFF = PS_OFF + (size_t)NB * NS * CHA;
// fp16 region (element offsets):
constexpr size_t QT_H   = 0;                                  // q [b][s][c]
constexpr size_t KT_H   = QT_H + (size_t)NB * NS * NC;        // k [b][s][c]
constexpr size_t VT_H   = KT_H + (size_t)NB * NS * NC;        // v [b][c][s]
constexpr size_t W16_H  = VT_H + (size_t)NB * NS * NC;        // W16 [3][128][128]

// ---------------- K0: ragged lengths ----------------
__global__ void k_lens(const int* __restrict__ lm_t, const int* __restrict__ lm_r,
                       int* __restrict__ lens) {
    int b = blockIdx.x & 15;
    const int* src = (blockIdx.x < 16) ? lm_t : lm_r;
    src += b * 4096;
    int m = 0;
    for (int i = threadIdx.x; i < 4096; i += 256) m = max(m, src[i]);
    for (int off = 32; off; off >>= 1) m = max(m, __shfl_down(m, off, 64));
    __shared__ int red[4];
    if ((threadIdx.x & 63) == 0) red[threadIdx.x >> 6] = m;
    __syncthreads();
    if (threadIdx.x == 0) {
        m = max(max(red[0], red[1]), max(red[2], red[3]));
        lens[blockIdx.x] = m + 1;   // [0..15]=len_t, [16..31]=len_r
    }
}

// ---------------- K0b: convert W to fp16 ----------------
__global__ void k_prep(const float* __restrict__ Wq, const float* __restrict__ Wk,
                       const float* __restrict__ Wv, _Float16* __restrict__ W16) {
    int i = blockIdx.x * 256 + threadIdx.x;
    W16[i]               = (_Float16)Wq[i];
    W16[i + NC * NC]     = (_Float16)Wk[i];
    W16[i + 2 * NC * NC] = (_Float16)Wv[i];
}

// ---------------- K1: fused center-norm + projection GEMM (MFMA) ----------------
// MODE 0/1: out [b][s][c] fp16 (q,k); MODE 2: vout [b][c][s] fp16 (v)
template <bool NORM, int MODE>
__global__ __launch_bounds__(256) void k_qkv(const float* __restrict__ x,
                                             const _Float16* __restrict__ W16,
                                             const float* __restrict__ bias,
                                             _Float16* __restrict__ out,
                                             _Float16* __restrict__ vout) {
    __shared__ __align__(16) char smem[48 * 1024];
    float*    xs = (float*)smem;                        // [128][64] fp32 (32 KB)
    _Float16* xn = (_Float16*)(smem + 32 * 1024);       // [64][16 slots of 8] swizzled (16 KB)
    _Float16 (*Vt)[72] = (_Float16 (*)[72])smem;        // MODE2: [128][72] (18.4 KB, aliases xs)
    __shared__ float ps[4][64], pq[4][64], cmean[64], cscale[64];

    const int b  = blockIdx.y;
    const int s0 = blockIdx.x * 64;
    const float* xb = x + (size_t)b * NC * NS + s0;

    for (int idx = threadIdx.x; idx < NC * 16; idx += 256) {
        int c = idx >> 4, j = (idx & 15) << 2;
        *(float4*)&xs[c * 64 + j] = *(const float4*)&xb[(size_t)c * NS + j];
    }
    __syncthreads();

    if (NORM) {
        int j = threadIdx.x & 63, p = threadIdx.x >> 6;
        float sum = 0.f, ssq = 0.f;
#pragma unroll
        for (int cc = 0; cc < 32; ++cc) {
            float v = xs[(p * 32 + cc) * 64 + j];
            sum += v; ssq += v * v;
        }
        ps[p][j] = sum; pq[p][j] = ssq;
        __syncthreads();
        if (threadIdx.x < 64) {
            float sm = ps[0][j] + ps[1][j] + ps[2][j] + ps[3][j];
            float sq = pq[0][j] + pq[1][j] + pq[2][j] + pq[3][j];
            float mean = sm * (1.f / NC);
            float var = sq - (float)NC * mean * mean;
            cmean[j]  = mean;
            cscale[j] = 1.f / (sqrtf(fmaxf(var, 0.f)) + F_EPS);
        }
        __syncthreads();
    }

    // write normalized fp16 to xn[s][c] with XOR slot swizzle (s-row, 16 slots of 8 c)
    {
        const int lane = threadIdx.x & 63;           // s
        const int w4   = threadIdx.x >> 6;           // c chunk of 32
        const float mn = NORM ? cmean[lane] : 0.f;
        const float sc = NORM ? cscale[lane] : 1.f;
#pragma unroll
        for (int q = 0; q < 4; ++q) {
            f16x8 v8;
#pragma unroll
            for (int i = 0; i < 8; ++i)
                v8[i] = (_Float16)((xs[(w4 * 32 + q * 8 + i) * 64 + lane] - mn) * sc);
            *(f16x8*)(xn + lane * 128 + (((w4 * 4 + q) ^ (lane & 7)) << 3)) = v8;
        }
    }
    __syncthreads();   // xn ready; xs dead (Vt may alias it)

    const int w = threadIdx.x >> 6, lane = threadIdx.x & 63;
    const int ln = lane & 15, g = lane >> 4;
    const int sl = w * 16 + ln;                      // local s row (0..63)

    f16x8 xf[4];
#pragma unroll
    for (int jj = 0; jj < 4; ++jj)
        xf[jj] = *(const f16x8*)(xn + sl * 128 + (((jj * 4 + g) ^ (ln & 7)) << 3));

#pragma unroll
    for (int ot = 0; ot < 8; ++ot) {
        const _Float16* wrow = W16 + (size_t)(ot * 16 + ln) * NC + g * 8;
        f32x4 acc = {0.f, 0.f, 0.f, 0.f};
        acc = MFMA16(*(const f16x8*)(wrow),      xf[0], acc);
        acc = MFMA16(*(const f16x8*)(wrow + 32), xf[1], acc);
        acc = MFMA16(*(const f16x8*)(wrow + 64), xf[2], acc);
        acc = MFMA16(*(const f16x8*)(wrow + 96), xf[3], acc);
        const float4 bv = *(const float4*)&bias[ot * 16 + 4 * g];
        f16x4 res;
        res[0] = (_Float16)(acc[0] + bv.x);
        res[1] = (_Float16)(acc[1] + bv.y);
        res[2] = (_Float16)(acc[2] + bv.z);
        res[3] = (_Float16)(acc[3] + bv.w);
        if (MODE < 2) {
            *(f16x4*)(out + ((size_t)b * NS + s0 + sl) * NC + ot * 16 + 4 * g) = res;
        } else {
#pragma unroll
            for (int r = 0; r < 4; ++r)
                Vt[ot * 16 + 4 * g + r][sl] = res[r];
        }
    }
    if (MODE == 2) {
        __syncthreads();
        int o = threadIdx.x >> 1, sh = threadIdx.x & 1;
        _Float16* vr = vout + ((size_t)b * NC + o) * NS + s0 + sh * 32;
        const _Float16* src = &Vt[o][sh * 32];
#pragma unroll
        for (int i = 0; i < 4; ++i) *(f16x8*)(vr + i * 8) = *(const f16x8*)(src + i * 8);
    }
}

// ---------------- K3: partial softmax stats (split-m, 8 waves, prefetch) ----------------
__global__ __launch_bounds__(512, 6) void k_stats(const _Float16* __restrict__ qt,
                                                  const _Float16* __restrict__ kt,
                                                  const int* __restrict__ lens,
                                                  float* __restrict__ pM,
                                                  float* __restrict__ pS) {
    __shared__ _Float16 Klds[64 * 128];
    const int nt = blockIdx.x, ch = blockIdx.y, b = blockIdx.z;
    const int tid = threadIdx.x;
    const int w = tid >> 6, lane = tid & 63, ln = lane & 15, g = lane >> 4;
    const int n_base = nt * 128 + w * 16;
    const int lenr = lens[16 + b];
    const int swz = ln & 7;

    const _Float16* qrow = qt + ((size_t)b * NS + n_base + ln) * NC + g * 8;
    f16x8 qf[4];
#pragma unroll
    for (int j = 0; j < 4; ++j) qf[j] = *(const f16x8*)(qrow + 32 * j);

    const _Float16* kb = kt + (size_t)b * NS * NC;

    f16x8 kreg[2];
    auto load_k = [&](int mg0) {
#pragma unroll
        for (int q = 0; q < 2; ++q) {
            int idx = q * 512 + tid;
            kreg[q] = *(const f16x8*)(kb + (size_t)(mg0 + (idx >> 4)) * NC + (idx & 15) * 8);
        }
    };
    auto store_k = [&]() {
#pragma unroll
        for (int q = 0; q < 2; ++q) {
            int idx = q * 512 + tid;
            int r = idx >> 4, s = idx & 15;
            *(f16x8*)(Klds + r * 128 + ((s ^ (r & 7)) << 3)) = kreg[q];
        }
    };

    float mrun = NEGBIG, srun = 0.f;
    const int mg_first = ch * (NS / CHA);
    const int m_end = min(mg_first + NS / CHA, lenr);
    if (mg_first < lenr) {
        load_k(mg_first);
        for (int mg0 = mg_first; mg0 < m_end; mg0 += 64) {
            __syncthreads();
            store_k();
            if (mg0 + 64 < m_end) load_k(mg0 + 64);
            __syncthreads();
#pragma unroll
            for (int half = 0; half < 2; ++half) {
                const int m0 = half * 32;
                f32x4 a0 = {0.f, 0.f, 0.f, 0.f}, a1 = {0.f, 0.f, 0.f, 0.f};
#pragma unroll
                for (int j = 0; j < 4; ++j) {
                    f16x8 k0 = *(const f16x8*)(Klds + (m0 + ln) * 128 + ((((j << 2) + g) ^ swz) << 3));
                    f16x8 k1 = *(const f16x8*)(Klds + (m0 + 16 + ln) * 128 + ((((j << 2) + g) ^ swz) << 3));
                    a0 = MFMA16(k0, qf[j], a0);
                    a1 = MFMA16(k1, qf[j], a1);
                }
                float vv[8];
#pragma unroll
                for (int r = 0; r < 4; ++r) {
                    int mi = mg0 + m0 + 4 * g + r;
                    vv[r]     = (mi      < lenr) ? a0[r] * F_INV_TEMP : NEGBIG;
                    vv[4 + r] = (mi + 16 < lenr) ? a1[r] * F_INV_TEMP : NEGBIG;
                }
                float cmax = fmaxf(fmaxf(fmaxf(vv[0], vv[1]), fmaxf(vv[2], vv[3])),
                                   fmaxf(fmaxf(vv[4], vv[5]), fmaxf(vv[6], vv[7])));
                float newm = fmaxf(mrun, cmax);
                float ssum = 0.f;
#pragma unroll
                for (int i = 0; i < 8; ++i) ssum += __expf(vv[i] - newm);
                srun = srun * __expf(mrun - newm) + ssum;
                mrun = newm;
            }
        }
    }
#pragma unroll
    for (int off = 16; off <= 32; off <<= 1) {
        float om = __shfl_xor(mrun, off, 64);
        float os = __shfl_xor(srun, off, 64);
        float nm = fmaxf(mrun, om);
        srun = srun * __expf(mrun - nm) + os * __expf(om - nm);
        mrun = nm;
    }
    if (g == 0) {
        size_t row = (size_t)b * NS + n_base + ln;
        pM[row * CHA + ch] = mrun;
        pS[row * CHA + ch] = srun;
    }
}

// ---------------- K4: combine partials ----------------
__global__ void k_combine(const float* __restrict__ pM, const float* __restrict__ pS,
                          const int* __restrict__ lens,
                          float* __restrict__ rM, float* __restrict__ rI) {
    int row = blockIdx.x * 256 + threadIdx.x;
    int b = row >> 11, n = row & (NS - 1);
    float M = NEGBIG;
#pragma unroll
    for (int c = 0; c < CHA; ++c) M = fmaxf(M, pM[(size_t)row * CHA + c]);
    float S = 0.f;
#pragma unroll
    for (int c = 0; c < CHA; ++c) {
        float pm = pM[(size_t)row * CHA + c];
        if (pm > -1e29f) S += pS[(size_t)row * CHA + c] * __expf(pm - M);
    }
    rM[row] = M;
    rI[row] = (n < lens[b]) ? 1.f / S : 0.f;
}

// ---------------- K5: pass B — recompute QK^T, write att, partial PV ----------------
__global__ __launch_bounds__(512, 4) void k_attn2(const _Float16* __restrict__ qt,
                                                  const _Float16* __restrict__ kt,
                                                  const _Float16* __restrict__ vt,
                                                  const int* __restrict__ lens,
                                                  const float* __restrict__ rM,
                                                  const float* __restrict__ rI,
                                                  float* __restrict__ att,
                                                  float* __restrict__ out0) {
    __shared__ _Float16 Klds[64 * 128];
    __shared__ _Float16 Vlds[128 * 64];
    __shared__ _Float16 Plds[8][16][40];
    const int nt = blockIdx.x, ch = blockIdx.y, b = blockIdx.z;
    const int tid = threadIdx.x;
    const int w = tid >> 6, lane = tid & 63, ln = lane & 15, g = lane >> 4;
    const int n_base = nt * 128 + w * 16;
    const int lenr = lens[16 + b];
    const int swz = ln & 7;

    const _Float16* qrow = qt + ((size_t)b * NS + n_base + ln) * NC + g * 8;
    f16x8 qf[4];
#pragma unroll
    for (int j = 0; j < 4; ++j) qf[j] = *(const f16x8*)(qrow + 32 * j);

    const _Float16* kb = kt + (size_t)b * NS * NC;   // [m][c]
    const _Float16* vb = vt + (size_t)b * NC * NS;   // [c][m]

    const size_t row = (size_t)b * NS + n_base + ln;
    const float M = rM[row];
    const float rinv = rI[row];

    f32x4 opv[8];
#pragma unroll
    for (int ct = 0; ct < 8; ++ct) opv[ct] = f32x4{0.f, 0.f, 0.f, 0.f};

    float* attb = att + row * NS;

    f16x8 kreg[2], vreg[2];
    auto load_kv = [&](int mg0) {
#pragma unroll
        for (int q = 0; q < 2; ++q) {
            int idx = q * 512 + tid;
            kreg[q] = *(const f16x8*)(kb + (size_t)(mg0 + (idx >> 4)) * NC + (idx & 15) * 8);
            vreg[q] = *(const f16x8*)(vb + (size_t)(idx >> 3) * NS + mg0 + (idx & 7) * 8);
        }
    };
    auto store_kv = [&]() {
#pragma unroll
        for (int q = 0; q < 2; ++q) {
            int idx = q * 512 + tid;
            int r = idx >> 4, s = idx & 15;
            *(f16x8*)(Klds + r * 128 + ((s ^ (r & 7)) << 3)) = kreg[q];
            int rv = idx >> 3, sv = idx & 7;
            *(f16x8*)(Vlds + rv * 64 + ((sv ^ (rv & 7)) << 3)) = vreg[q];
        }
    };

    constexpr int NT = (NS / CHB) / 64;
    load_kv(ch * (NS / CHB));
    for (int it = 0; it < NT; ++it) {
        const int mg0 = ch * (NS / CHB) + it * 64;
        const bool live = (mg0 < lenr);              // block-uniform
        __syncthreads();
        if (live) store_kv();
        if (it + 1 < NT) load_kv(mg0 + 64);
        __syncthreads();
        if (!live) {
            f32x4 z = {0.f, 0.f, 0.f, 0.f};
#pragma unroll
            for (int h = 0; h < 4; ++h)
                *(f32x4*)(attb + mg0 + h * 16 + 4 * g) = z;
            continue;
        }
#pragma unroll
        for (int half = 0; half < 2; ++half) {
            const int m0 = half * 32;
            f32x4 a0 = {0.f, 0.f, 0.f, 0.f}, a1 = {0.f, 0.f, 0.f, 0.f};
#pragma unroll
            for (int j = 0; j < 4; ++j) {
                f16x8 k0 = *(const f16x8*)(Klds + (m0 + ln) * 128 + ((((j << 2) + g) ^ swz) << 3));
                f16x8 k1 = *(const f16x8*)(Klds + (m0 + 16 + ln) * 128 + ((((j << 2) + g) ^ swz) << 3));
                a0 = MFMA16(k0, qf[j], a0);
                a1 = MFMA16(k1, qf[j], a1);
            }
            f32x4 p0, p1;
#pragma unroll
            for (int r = 0; r < 4; ++r) {
                int mi = mg0 + m0 + 4 * g + r;
                float v0 = (mi      < lenr) ? a0[r] * F_INV_TEMP : NEGBIG;
                float v1 = (mi + 16 < lenr) ? a1[r] * F_INV_TEMP : NEGBIG;
                p0[r] = __expf(v0 - M) * rinv;
                p1[r] = __expf(v1 - M) * rinv;
            }
            *(f32x4*)(attb + mg0 + m0 + 4 * g)      = p0;
            *(f32x4*)(attb + mg0 + m0 + 16 + 4 * g) = p1;

            f16x4 pk0, pk1;
#pragma unroll
            for (int r = 0; r < 4; ++r) {
                pk0[r] = (_Float16)p0[r];
                pk1[r] = (_Float16)p1[r];
            }
            *(f16x4*)&Plds[w][ln][4 * g]      = pk0;
            *(f16x4*)&Plds[w][ln][16 + 4 * g] = pk1;
            f16x8 pf = *(const f16x8*)&Plds[w][ln][g * 8];

#pragma unroll
            for (int ct = 0; ct < 8; ++ct) {
                f16x8 vf = *(const f16x8*)(Vlds + (ct * 16 + ln) * 64 +
                                           (((half * 4 + g) ^ swz) << 3));
                opv[ct] = MFMA16(pf, vf, opv[ct]);
            }
        }
    }

    // partial PV -> out0 (exactly CHB=2 adds per element: bitwise deterministic)
    float* ob = out0 + (size_t)b * NC * NS;
#pragma unroll
    for (int ct = 0; ct < 8; ++ct) {
        float* dst = ob + (size_t)(ct * 16 + ln) * NS + n_base + 4 * g;
#pragma unroll
        for (int r = 0; r < 4; ++r) unsafeAtomicAdd(dst + r, opv[ct][r]);
    }
}

// ---------------- launch ----------------
extern "C" void kernel_launch(void* const* d_in, const int* in_sizes, int n_in,
                              void* d_out, int out_size, void* d_ws, size_t ws_size,
                              hipStream_t stream) {
    const float* xt   = (const float*)d_in[0];
    const float* xr   = (const float*)d_in[1];
    const int*   lmt  = (const int*)d_in[2];
    const int*   lmr  = (const int*)d_in[3];
    const float* xrgb = (const float*)d_in[6];
    const float* Wq   = (const float*)d_in[9];
    const float* bq   = (const float*)d_in[10];
    const float* Wk   = (const float*)d_in[11];
    const float* bk   = (const float*)d_in[12];
    const float* Wv   = (const float*)d_in[13];
    const float* bv   = (const float*)d_in[14];

    float* out0 = (float*)d_out;                       // [NB][NC][NS]
    float* att  = out0 + (size_t)NB * NC * NS;         // [NB][NS][NS]

    float* ws   = (float*)d_ws;
    int*   lens = (int*)d_ws;
    _Float16* h = (_Float16*)(ws + F16_OFF);
    _Float16* qt  = h + QT_H;
    _Float16* kt  = h + KT_H;
    _Float16* vt  = h + VT_H;
    _Float16* W16 = h + W16_H;

    k_lens<<<32, 256, 0, stream>>>(lmt, lmr, lens);
    k_prep<<<NC * NC / 256, 256, 0, stream>>>(Wq, Wk, Wv, W16);

    dim3 gproj(NS / 64, NB);
    k_qkv<true,  0><<<gproj, 256, 0, stream>>>(xt,   W16,               bq, qt, nullptr);
    k_qkv<true,  1><<<gproj, 256, 0, stream>>>(xr,   W16 + NC * NC,     bk, kt, nullptr);
    k_qkv<false, 2><<<gproj, 256, 0, stream>>>(xrgb, W16 + 2 * NC * NC, bv, nullptr, vt);

    dim3 gstats(NS / 128, CHA, NB);
    k_stats<<<gstats, 512, 0, stream>>>(qt, kt, lens, ws + PM_OFF, ws + PS_OFF);
    k_combine<<<(NB * NS) / 256, 256, 0, stream>>>(ws + PM_OFF, ws + PS_OFF, lens,
                                                   ws + RM_OFF, ws + RI_OFF);

    hipMemsetAsync(out0, 0, (size_t)NB * NC * NS * sizeof(float), stream);

    dim3 gattn(NS / 128, CHB, NB);
    k_attn2<<<gattn, 512, 0, stream>>>(qt, kt, vt, lens, ws + RM_OFF, ws + RI_OFF,
                                       att, out0);
}

// Round 6
// 250.699 us; speedup vs baseline: 3.2744x; 1.0054x over previous
//
#include <hip/hip_runtime.h>
#include <math.h>

constexpr int NB = 16;
constexpr int NC = 128;
constexpr int NS = 2048;          // Np1 == Mp1 == S
constexpr float F_INV_TEMP = 100.0f;
constexpr float F_EPS = 1e-5f;
constexpr float NEGBIG = -1e30f;
constexpr int CHA = 4;            // stats m-chunks (512 each)
constexpr int CHB = 2;            // pass-B m-chunks (1024 each)

typedef __attribute__((ext_vector_type(8))) _Float16 f16x8;
typedef __attribute__((ext_vector_type(4))) _Float16 f16x4;
typedef __attribute__((ext_vector_type(4))) float f32x4;

#define MFMA16(a, b, c) __builtin_amdgcn_mfma_f32_16x16x32_f16((a), (b), (c), 0, 0, 0)
#define GLOAD_LDS(g, l) __builtin_amdgcn_global_load_lds(                      \
    (const __attribute__((address_space(1))) void*)(g),                       \
    (__attribute__((address_space(3))) void*)(l), 16, 0, 0)
#define SBAR()   __builtin_amdgcn_s_barrier()
#define WAITV(N) asm volatile("s_waitcnt vmcnt(" #N ")" ::: "memory")
#define SCHED0() __builtin_amdgcn_sched_barrier(0)

// ---- workspace layout (float offsets) ----
constexpr size_t RM_OFF = 64;                        // rowmax [NB*NS]
constexpr size_t RI_OFF = RM_OFF + (size_t)NB * NS;  // rowinv [NB*NS]
constexpr size_t PM_OFF = RI_OFF + (size_t)NB * NS;  // partial max [NB*NS][CHA]
constexpr size_t PS_OFF = PM_OFF + (size_t)NB * NS * CHA;
constexpr size_t F16_OFF = PS_OFF + (size_t)NB * NS * CHA;
// fp16 region (element offsets):
constexpr size_t QT_H   = 0;                                  // q [b][s][c]
constexpr size_t KT_H   = QT_H + (size_t)NB * NS * NC;        // k [b][s][c]
constexpr size_t VT_H   = KT_H + (size_t)NB * NS * NC;        // v [b][c][s]
constexpr size_t W16_H  = VT_H + (size_t)NB * NS * NC;        // W16 [3][128][128]

// ---------------- K0: ragged lengths ----------------
__global__ void k_lens(const int* __restrict__ lm_t, const int* __restrict__ lm_r,
                       int* __restrict__ lens) {
    int b = blockIdx.x & 15;
    const int* src = (blockIdx.x < 16) ? lm_t : lm_r;
    src += b * 4096;
    int m = 0;
    for (int i = threadIdx.x; i < 4096; i += 256) m = max(m, src[i]);
    for (int off = 32; off; off >>= 1) m = max(m, __shfl_down(m, off, 64));
    __shared__ int red[4];
    if ((threadIdx.x & 63) == 0) red[threadIdx.x >> 6] = m;
    __syncthreads();
    if (threadIdx.x == 0) {
        m = max(max(red[0], red[1]), max(red[2], red[3]));
        lens[blockIdx.x] = m + 1;   // [0..15]=len_t, [16..31]=len_r
    }
}

// ---------------- K0b: convert W to fp16 ----------------
__global__ void k_prep(const float* __restrict__ Wq, const float* __restrict__ Wk,
                       const float* __restrict__ Wv, _Float16* __restrict__ W16) {
    int i = blockIdx.x * 256 + threadIdx.x;
    W16[i]               = (_Float16)Wq[i];
    W16[i + NC * NC]     = (_Float16)Wk[i];
    W16[i + 2 * NC * NC] = (_Float16)Wv[i];
}

// ---------------- K1: fused center-norm + projection GEMM (MFMA) ----------------
// MODE 0/1: out [b][s][c] fp16 (q,k); MODE 2: vout [b][c][s] fp16 (v)
template <bool NORM, int MODE>
__global__ __launch_bounds__(256) void k_qkv(const float* __restrict__ x,
                                             const _Float16* __restrict__ W16,
                                             const float* __restrict__ bias,
                                             _Float16* __restrict__ out,
                                             _Float16* __restrict__ vout) {
    __shared__ __align__(16) char smem[48 * 1024];
    float*    xs = (float*)smem;                        // [128][64] fp32 (32 KB)
    _Float16* xn = (_Float16*)(smem + 32 * 1024);       // [64][16 slots of 8] swizzled (16 KB)
    _Float16 (*Vt)[72] = (_Float16 (*)[72])smem;        // MODE2: [128][72] aliases xs
    __shared__ float ps[4][64], pq[4][64], cmean[64], cscale[64];

    const int b  = blockIdx.y;
    const int s0 = blockIdx.x * 64;
    const float* xb = x + (size_t)b * NC * NS + s0;

    for (int idx = threadIdx.x; idx < NC * 16; idx += 256) {
        int c = idx >> 4, j = (idx & 15) << 2;
        *(float4*)&xs[c * 64 + j] = *(const float4*)&xb[(size_t)c * NS + j];
    }
    __syncthreads();

    if (NORM) {
        int j = threadIdx.x & 63, p = threadIdx.x >> 6;
        float sum = 0.f, ssq = 0.f;
#pragma unroll
        for (int cc = 0; cc < 32; ++cc) {
            float v = xs[(p * 32 + cc) * 64 + j];
            sum += v; ssq += v * v;
        }
        ps[p][j] = sum; pq[p][j] = ssq;
        __syncthreads();
        if (threadIdx.x < 64) {
            float sm = ps[0][j] + ps[1][j] + ps[2][j] + ps[3][j];
            float sq = pq[0][j] + pq[1][j] + pq[2][j] + pq[3][j];
            float mean = sm * (1.f / NC);
            float var = sq - (float)NC * mean * mean;
            cmean[j]  = mean;
            cscale[j] = 1.f / (sqrtf(fmaxf(var, 0.f)) + F_EPS);
        }
        __syncthreads();
    }

    {
        const int lane = threadIdx.x & 63;           // s
        const int w4   = threadIdx.x >> 6;           // c chunk of 32
        const float mn = NORM ? cmean[lane] : 0.f;
        const float sc = NORM ? cscale[lane] : 1.f;
#pragma unroll
        for (int q = 0; q < 4; ++q) {
            f16x8 v8;
#pragma unroll
            for (int i = 0; i < 8; ++i)
                v8[i] = (_Float16)((xs[(w4 * 32 + q * 8 + i) * 64 + lane] - mn) * sc);
            *(f16x8*)(xn + lane * 128 + (((w4 * 4 + q) ^ (lane & 7)) << 3)) = v8;
        }
    }
    __syncthreads();   // xn ready; xs dead (Vt may alias it)

    const int w = threadIdx.x >> 6, lane = threadIdx.x & 63;
    const int ln = lane & 15, g = lane >> 4;
    const int sl = w * 16 + ln;                      // local s row (0..63)

    f16x8 xf[4];
#pragma unroll
    for (int jj = 0; jj < 4; ++jj)
        xf[jj] = *(const f16x8*)(xn + sl * 128 + (((jj * 4 + g) ^ (ln & 7)) << 3));

#pragma unroll
    for (int ot = 0; ot < 8; ++ot) {
        const _Float16* wrow = W16 + (size_t)(ot * 16 + ln) * NC + g * 8;
        f32x4 acc = {0.f, 0.f, 0.f, 0.f};
        acc = MFMA16(*(const f16x8*)(wrow),      xf[0], acc);
        acc = MFMA16(*(const f16x8*)(wrow + 32), xf[1], acc);
        acc = MFMA16(*(const f16x8*)(wrow + 64), xf[2], acc);
        acc = MFMA16(*(const f16x8*)(wrow + 96), xf[3], acc);
        const float4 bv = *(const float4*)&bias[ot * 16 + 4 * g];
        f16x4 res;
        res[0] = (_Float16)(acc[0] + bv.x);
        res[1] = (_Float16)(acc[1] + bv.y);
        res[2] = (_Float16)(acc[2] + bv.z);
        res[3] = (_Float16)(acc[3] + bv.w);
        if (MODE < 2) {
            *(f16x4*)(out + ((size_t)b * NS + s0 + sl) * NC + ot * 16 + 4 * g) = res;
        } else {
#pragma unroll
            for (int r = 0; r < 4; ++r)
                Vt[ot * 16 + 4 * g + r][sl] = res[r];
        }
    }
    if (MODE == 2) {
        __syncthreads();
        int o = threadIdx.x >> 1, sh = threadIdx.x & 1;
        _Float16* vr = vout + ((size_t)b * NC + o) * NS + s0 + sh * 32;
        const _Float16* src = &Vt[o][sh * 32];
#pragma unroll
        for (int i = 0; i < 4; ++i) *(f16x8*)(vr + i * 8) = *(const f16x8*)(src + i * 8);
    }
}

// ---------------- K3: partial softmax stats (split-m, async pipeline) ----------------
__global__ __launch_bounds__(512, 6) void k_stats(const _Float16* __restrict__ qt,
                                                  const _Float16* __restrict__ kt,
                                                  const int* __restrict__ lens,
                                                  float* __restrict__ pM,
                                                  float* __restrict__ pS) {
    __shared__ __align__(16) _Float16 Kl[2][64 * 128];
    const int nt = blockIdx.x, ch = blockIdx.y, b = blockIdx.z;
    const int tid = threadIdx.x;
    const int w = tid >> 6, lane = tid & 63, ln = lane & 15, g = lane >> 4;
    const int n_base = nt * 128 + w * 16;
    const int lenr = lens[16 + b];
    const int swz = ln & 7;

    const _Float16* qrow = qt + ((size_t)b * NS + n_base + ln) * NC + g * 8;
    f16x8 qf[4];
#pragma unroll
    for (int j = 0; j < 4; ++j) qf[j] = *(const f16x8*)(qrow + 32 * j);

    const _Float16* kb = kt + (size_t)b * NS * NC;

    // per-lane pre-swizzled global offsets (linear LDS dest, inverse-swz source)
    size_t goffk[2];
#pragma unroll
    for (int q = 0; q < 2; ++q) {
        const int ck = w * 2 + q;                 // K chunk 0..15
        const int r  = ck * 4 + (lane >> 4);
        const int j  = lane & 15;
        goffk[q] = (size_t)r * NC + ((j ^ (r & 7)) << 3);
    }
    const int mbase = ch * (NS / CHA);
    constexpr int NTS = (NS / CHA) / 64;          // 8

    auto stage = [&](int bf, int t) {
        const _Float16* ks = kb + (size_t)(mbase + t * 64) * NC;
#pragma unroll
        for (int q = 0; q < 2; ++q)
            GLOAD_LDS(ks + goffk[q], &Kl[bf][(w * 2 + q) * 512]);
    };

    float mrun = NEGBIG, srun = 0.f;
    stage(0, 0);
    for (int t = 0; t < NTS; ++t) {
        const int cur = t & 1;
        const int mg0 = mbase + t * 64;
        if (t + 1 < NTS) { stage(cur ^ 1, t + 1); WAITV(2); }
        else             { WAITV(0); }
        SBAR(); SCHED0();
#pragma unroll
        for (int half = 0; half < 2; ++half) {
            const int m0 = half * 32;
            f32x4 a0 = {0.f, 0.f, 0.f, 0.f}, a1 = {0.f, 0.f, 0.f, 0.f};
#pragma unroll
            for (int j = 0; j < 4; ++j) {
                f16x8 k0 = *(const f16x8*)&Kl[cur][(m0 + ln) * 128 + ((((j << 2) + g) ^ swz) << 3)];
                f16x8 k1 = *(const f16x8*)&Kl[cur][(m0 + 16 + ln) * 128 + ((((j << 2) + g) ^ swz) << 3)];
                a0 = MFMA16(k0, qf[j], a0);
                a1 = MFMA16(k1, qf[j], a1);
            }
            float vv[8];
#pragma unroll
            for (int r = 0; r < 4; ++r) {
                int mi = mg0 + m0 + 4 * g + r;
                vv[r]     = (mi      < lenr) ? a0[r] * F_INV_TEMP : NEGBIG;
                vv[4 + r] = (mi + 16 < lenr) ? a1[r] * F_INV_TEMP : NEGBIG;
            }
            float cmax = fmaxf(fmaxf(fmaxf(vv[0], vv[1]), fmaxf(vv[2], vv[3])),
                               fmaxf(fmaxf(vv[4], vv[5]), fmaxf(vv[6], vv[7])));
            float newm = fmaxf(mrun, cmax);
            float ssum = 0.f;
#pragma unroll
            for (int i = 0; i < 8; ++i) ssum += __expf(vv[i] - newm);
            srun = srun * __expf(mrun - newm) + ssum;
            mrun = newm;
        }
        SBAR();
    }
#pragma unroll
    for (int off = 16; off <= 32; off <<= 1) {
        float om = __shfl_xor(mrun, off, 64);
        float os = __shfl_xor(srun, off, 64);
        float nm = fmaxf(mrun, om);
        srun = srun * __expf(mrun - nm) + os * __expf(om - nm);
        mrun = nm;
    }
    if (g == 0) {
        size_t row = (size_t)b * NS + n_base + ln;
        pM[row * CHA + ch] = mrun;
        pS[row * CHA + ch] = srun;
    }
}

// ---------------- K4: combine partials ----------------
__global__ void k_combine(const float* __restrict__ pM, const float* __restrict__ pS,
                          const int* __restrict__ lens,
                          float* __restrict__ rM, float* __restrict__ rI) {
    int row = blockIdx.x * 256 + threadIdx.x;
    int b = row >> 11, n = row & (NS - 1);
    float M = NEGBIG;
#pragma unroll
    for (int c = 0; c < CHA; ++c) M = fmaxf(M, pM[(size_t)row * CHA + c]);
    float S = 0.f;
#pragma unroll
    for (int c = 0; c < CHA; ++c) {
        float pm = pM[(size_t)row * CHA + c];
        if (pm > -1e29f) S += pS[(size_t)row * CHA + c] * __expf(pm - M);
    }
    rM[row] = M;
    rI[row] = (n < lens[b]) ? 1.f / S : 0.f;
}

// ---------------- K5: pass B — recompute QK^T, write att, partial PV ----------------
// Double-buffered global_load_lds pipeline; raw s_barrier + counted vmcnt so att
// stores and prefetch loads stay in flight across barriers (no vmcnt(0) drains).
__global__ __launch_bounds__(512, 4) void k_attn2(const _Float16* __restrict__ qt,
                                                  const _Float16* __restrict__ kt,
                                                  const _Float16* __restrict__ vt,
                                                  const int* __restrict__ lens,
                                                  const float* __restrict__ rM,
                                                  const float* __restrict__ rI,
                                                  float* __restrict__ att,
                                                  float* __restrict__ out0) {
    extern __shared__ __align__(16) _Float16 dsm[];
    _Float16* Kl = dsm;                       // [2][64*128]
    _Float16* Vl = dsm + 2 * 64 * 128;        // [2][128*64]
    _Float16* Pl = Vl + 2 * 128 * 64;         // [8][16][40]

    const int nt = blockIdx.x, ch = blockIdx.y, b = blockIdx.z;
    const int tid = threadIdx.x;
    const int w = tid >> 6, lane = tid & 63, ln = lane & 15, g = lane >> 4;
    const int n_base = nt * 128 + w * 16;
    const int lenr = lens[16 + b];
    const int swz = ln & 7;

    const _Float16* qrow = qt + ((size_t)b * NS + n_base + ln) * NC + g * 8;
    f16x8 qf[4];
#pragma unroll
    for (int j = 0; j < 4; ++j) qf[j] = *(const f16x8*)(qrow + 32 * j);

    const _Float16* kb = kt + (size_t)b * NS * NC;   // [m][c]
    const _Float16* vb = vt + (size_t)b * NC * NS;   // [c][m]

    const size_t row = (size_t)b * NS + n_base + ln;
    const float M = rM[row];
    const float rinv = rI[row];

    // per-lane pre-swizzled global offsets (linear LDS dest, inverse-swz source)
    size_t goffk[2], goffv[2];
#pragma unroll
    for (int q = 0; q < 2; ++q) {
        const int ck = w * 2 + q;                 // chunk 0..15
        const int r  = ck * 4 + (lane >> 4);      // K row in tile
        const int j  = lane & 15;
        goffk[q] = (size_t)r * NC + ((j ^ (r & 7)) << 3);
        const int rv = ck * 8 + (lane >> 3);      // V channel
        const int sv = lane & 7;
        goffv[q] = (size_t)rv * NS + ((sv ^ (rv & 7)) << 3);
    }
    const int mbase = ch * (NS / CHB);
    constexpr int NT = (NS / CHB) / 64;           // 16

    auto stage = [&](int bf, int t) {
        const int mg0 = mbase + t * 64;
        const _Float16* ks = kb + (size_t)mg0 * NC;
        const _Float16* vs = vb + mg0;
#pragma unroll
        for (int q = 0; q < 2; ++q) {
            const int ck = w * 2 + q;
            GLOAD_LDS(ks + goffk[q], Kl + bf * 8192 + ck * 512);
            GLOAD_LDS(vs + goffv[q], Vl + bf * 8192 + ck * 512);
        }
    };

    f32x4 opv[8];
#pragma unroll
    for (int ct = 0; ct < 8; ++ct) opv[ct] = f32x4{0.f, 0.f, 0.f, 0.f};

    float* attb = att + row * NS;
    _Float16* Pw = Pl + w * 640;                  // this wave's P tile [16][40]

    stage(0, 0);
    for (int t = 0; t < NT; ++t) {
        const int cur = t & 1;
        const int mg0 = mbase + t * 64;
        if (t + 1 < NT) stage(cur ^ 1, t + 1);
        // steady state: allow 4 att stores(t-1) + 4 loads(t+1) outstanding;
        // first iter: no stores yet; last iter: no loads issued.
        if (t == 0 || t + 1 == NT) { WAITV(4); } else { WAITV(8); }
        SBAR(); SCHED0();

        const _Float16* Kc = Kl + cur * 8192;
        const _Float16* Vc = Vl + cur * 8192;
#pragma unroll
        for (int half = 0; half < 2; ++half) {
            const int m0 = half * 32;
            f32x4 a0 = {0.f, 0.f, 0.f, 0.f}, a1 = {0.f, 0.f, 0.f, 0.f};
            __builtin_amdgcn_s_setprio(1);
#pragma unroll
            for (int j = 0; j < 4; ++j) {
                f16x8 k0 = *(const f16x8*)&Kc[(m0 + ln) * 128 + ((((j << 2) + g) ^ swz) << 3)];
                f16x8 k1 = *(const f16x8*)&Kc[(m0 + 16 + ln) * 128 + ((((j << 2) + g) ^ swz) << 3)];
                a0 = MFMA16(k0, qf[j], a0);
                a1 = MFMA16(k1, qf[j], a1);
            }
            __builtin_amdgcn_s_setprio(0);
            f32x4 p0, p1;
#pragma unroll
            for (int r = 0; r < 4; ++r) {
                int mi = mg0 + m0 + 4 * g + r;
                float v0 = (mi      < lenr) ? a0[r] * F_INV_TEMP : NEGBIG;
                float v1 = (mi + 16 < lenr) ? a1[r] * F_INV_TEMP : NEGBIG;
                p0[r] = __expf(v0 - M) * rinv;    // masked -> exactly 0
                p1[r] = __expf(v1 - M) * rinv;
            }
            *(f32x4*)(attb + mg0 + m0 + 4 * g)      = p0;
            *(f32x4*)(attb + mg0 + m0 + 16 + 4 * g) = p1;

            f16x4 pk0, pk1;
#pragma unroll
            for (int r = 0; r < 4; ++r) {
                pk0[r] = (_Float16)p0[r];
                pk1[r] = (_Float16)p1[r];
            }
            *(f16x4*)&Pw[ln * 40 + 4 * g]      = pk0;
            *(f16x4*)&Pw[ln * 40 + 16 + 4 * g] = pk1;
            f16x8 pf = *(const f16x8*)&Pw[ln * 40 + g * 8];

            __builtin_amdgcn_s_setprio(1);
#pragma unroll
            for (int ct = 0; ct < 8; ++ct) {
                f16x8 vf = *(const f16x8*)&Vc[(ct * 16 + ln) * 64 +
                                              (((half * 4 + g) ^ swz) << 3)];
                opv[ct] = MFMA16(pf, vf, opv[ct]);
            }
            __builtin_amdgcn_s_setprio(0);
        }
        SBAR();   // all waves done reading buf[cur] before it is re-staged
    }

    // partial PV -> out0 (exactly CHB=2 adds per element: bitwise deterministic)
    float* ob = out0 + (size_t)b * NC * NS;
#pragma unroll
    for (int ct = 0; ct < 8; ++ct) {
        float* dst = ob + (size_t)(ct * 16 + ln) * NS + n_base + 4 * g;
#pragma unroll
        for (int r = 0; r < 4; ++r) unsafeAtomicAdd(dst + r, opv[ct][r]);
    }
}

// ---------------- launch ----------------
extern "C" void kernel_launch(void* const* d_in, const int* in_sizes, int n_in,
                              void* d_out, int out_size, void* d_ws, size_t ws_size,
                              hipStream_t stream) {
    const float* xt   = (const float*)d_in[0];
    const float* xr   = (const float*)d_in[1];
    const int*   lmt  = (const int*)d_in[2];
    const int*   lmr  = (const int*)d_in[3];
    const float* xrgb = (const float*)d_in[6];
    const float* Wq   = (const float*)d_in[9];
    const float* bq   = (const float*)d_in[10];
    const float* Wk   = (const float*)d_in[11];
    const float* bk   = (const float*)d_in[12];
    const float* Wv   = (const float*)d_in[13];
    const float* bv   = (const float*)d_in[14];

    float* out0 = (float*)d_out;                       // [NB][NC][NS]
    float* att  = out0 + (size_t)NB * NC * NS;         // [NB][NS][NS]

    float* ws   = (float*)d_ws;
    int*   lens = (int*)d_ws;
    _Float16* h = (_Float16*)(ws + F16_OFF);
    _Float16* qt  = h + QT_H;
    _Float16* kt  = h + KT_H;
    _Float16* vt  = h + VT_H;
    _Float16* W16 = h + W16_H;

    k_lens<<<32, 256, 0, stream>>>(lmt, lmr, lens);
    k_prep<<<NC * NC / 256, 256, 0, stream>>>(Wq, Wk, Wv, W16);

    dim3 gproj(NS / 64, NB);
    k_qkv<true,  0><<<gproj, 256, 0, stream>>>(xt,   W16,               bq, qt, nullptr);
    k_qkv<true,  1><<<gproj, 256, 0, stream>>>(xr,   W16 + NC * NC,     bk, kt, nullptr);
    k_qkv<false, 2><<<gproj, 256, 0, stream>>>(xrgb, W16 + 2 * NC * NC, bv, nullptr, vt);

    dim3 gstats(NS / 128, CHA, NB);
    k_stats<<<gstats, 512, 0, stream>>>(qt, kt, lens, ws + PM_OFF, ws + PS_OFF);
    k_combine<<<(NB * NS) / 256, 256, 0, stream>>>(ws + PM_OFF, ws + PS_OFF, lens,
                                                   ws + RM_OFF, ws + RI_OFF);

    hipMemsetAsync(out0, 0, (size_t)NB * NC * NS * sizeof(float), stream);

    const size_t attn_lds = (2 * 64 * 128 + 2 * 128 * 64 + 8 * 16 * 40) * sizeof(_Float16);
    dim3 gattn(NS / 128, CHB, NB);
    k_attn2<<<gattn, 512, attn_lds, stream>>>(qt, kt, vt, lens, ws + RM_OFF, ws + RI_OFF,
                                              att, out0);
}